// Round 19
// baseline (835.510 us; speedup 1.0000x reference)
//
#include <hip/hip_runtime.h>
#include <math.h>

#define NTOT   32768
#define DMODEL 256
#define EDGES  1048576
#define BGRAPH 128
#define NNODE  256
#define NHEAD  8
#define DHEAD  32
#define NLAYER 4
#define DIN    64
#define BNS    0.9999950000374997f   // 1/sqrt(1+1e-5)
#define CAPG   9216                   // per-graph edge bucket capacity

typedef short bf16x8 __attribute__((ext_vector_type(8)));
typedef float f32x4  __attribute__((ext_vector_type(4)));

__device__ __forceinline__ unsigned short f2b(float f) {
    union { float f; unsigned int u; } v; v.f = f;
    unsigned int r = v.u + 0x7FFFu + ((v.u >> 16) & 1u);  // RNE
    return (unsigned short)(r >> 16);
}
__device__ __forceinline__ float b2f(unsigned short u) {
    union { unsigned int u; float f; } v; v.u = ((unsigned int)u) << 16;
    return v.f;
}

// ---------------------------------------------------------------------------
// Pass 1: bucket edges by graph (L2-friendly coarse scatter).
// ---------------------------------------------------------------------------
__global__ __launch_bounds__(1024)
void k_bucket(const int* __restrict__ src, const int* __restrict__ dst,
              const float* __restrict__ ea, int* __restrict__ gcnt,
              uint2* __restrict__ gbuf) {
    __shared__ int hist[BGRAPH], base[BGRAPH], cur[BGRAPH];
    int t = threadIdx.x;
    int e0 = blockIdx.x * 4096;
    if (t < BGRAPH) { hist[t] = 0; cur[t] = 0; }
    __syncthreads();
    int g4[4]; unsigned int m4[4], a4[4];
#pragma unroll
    for (int j = 0; j < 4; ++j) {
        int e = e0 + j * 1024 + t;
        int s = src[e], d = dst[e];
        g4[j] = d >> 8;
        m4[j] = (unsigned int)(s & 255) | ((unsigned int)(d & 255) << 16);
        a4[j] = __float_as_uint(ea[e]);
        atomicAdd(&hist[g4[j]], 1);
    }
    __syncthreads();
    if (t < BGRAPH) base[t] = atomicAdd(&gcnt[t], hist[t]);
    __syncthreads();
#pragma unroll
    for (int j = 0; j < 4; ++j) {
        int g = g4[j];
        int slot = base[g] + atomicAdd(&cur[g], 1);
        if (slot < CAPG) {
            uint2 r; r.x = m4[j]; r.y = a4[j];
            gbuf[(size_t)g * CAPG + slot] = r;
        }
    }
}

// ---------------------------------------------------------------------------
// Pass 2: per-graph LDS counting sort -> CSR records + rowptr.
// ---------------------------------------------------------------------------
__global__ __launch_bounds__(1024)
void k_gsort(const uint2* __restrict__ gbuf, const int* __restrict__ gcnt,
             uint2* __restrict__ epk, int* __restrict__ rowptr) {
    __shared__ int s[NNODE], excl[NNODE + 1], cur[NNODE];
    int g = blockIdx.x;
    int c = gcnt[g];
    int t = threadIdx.x;
    size_t base = (size_t)g * CAPG;
    if (t < NNODE) { s[t] = 0; cur[t] = 0; }
    __syncthreads();
    for (int i = t; i < c; i += 1024)
        atomicAdd(&s[gbuf[base + i].x >> 16], 1);
    __syncthreads();
    for (int o = 1; o < NNODE; o <<= 1) {
        int add = (t < NNODE && t >= o) ? s[t - o] : 0;
        __syncthreads();
        if (t < NNODE) s[t] += add;
        __syncthreads();
    }
    if (t < NNODE) excl[t + 1] = s[t];
    if (t == 0) excl[0] = 0;
    __syncthreads();
    if (t <= NNODE) rowptr[g * (NNODE + 1) + t] = (int)base + excl[t];
    for (int i = t; i < c; i += 1024) {
        uint2 r = gbuf[base + i];
        int dl = r.x >> 16;
        int p = excl[dl] + atomicAdd(&cur[dl], 1);
        epk[base + p] = r;
    }
}

// ---------------------------------------------------------------------------
// Merged prologue: all weight convert+transpose jobs + mkvec + x->bf16.
// ---------------------------------------------------------------------------
__global__ __launch_bounds__(256)
void k_convall(const float* __restrict__ node_w, const float* __restrict__ gine_w1,
               const float* __restrict__ gine_w2, const float* __restrict__ attn_out_w,
               const float* __restrict__ attn_in_w, const float* __restrict__ mlp_w1,
               const float* __restrict__ mlp_w2,
               const float* __restrict__ bn1_g, const float* __restrict__ bn1_b,
               const float* __restrict__ bn2_g, const float* __restrict__ bn2_b,
               const float* __restrict__ bn3_g, const float* __restrict__ bn3_b,
               const float* __restrict__ gb2, const float* __restrict__ aob,
               const float* __restrict__ mb2, const float* __restrict__ x,
               unsigned short* __restrict__ w_node, unsigned short* __restrict__ w_g1,
               unsigned short* __restrict__ w_cat, unsigned short* __restrict__ w_ai,
               unsigned short* __restrict__ w_m1, unsigned short* __restrict__ w_m2s,
               float* __restrict__ biasC, float* __restrict__ rC,
               float* __restrict__ biasF, float* __restrict__ rF,
               unsigned short* __restrict__ xb) {
    __shared__ float tile[32][33];
    int bid = blockIdx.x;
    int t = threadIdx.x;

    if (bid >= 2580) {                        // f2b: x -> xb (bf16)
        int i = ((bid - 2580) * 256 + t) * 4;
        float4 v = *(const float4*)(x + i);
        xb[i + 0] = f2b(v.x); xb[i + 1] = f2b(v.y);
        xb[i + 2] = f2b(v.z); xb[i + 3] = f2b(v.w);
        return;
    }
    if (bid >= 2576) {                        // mkvec
        int i = (bid - 2576) * 256 + t;
        float s1 = bn1_g[i] * BNS, t1 = bn1_b[i];
        float s2 = bn2_g[i] * BNS, t2 = bn2_b[i];
        float s3 = bn3_g[i] * BNS, t3 = bn3_b[i];
        biasC[i] = gb2[i] * s1 + t1 + aob[i] * s2 + t2;
        rC[i]    = s1 + s2;
        biasF[i] = mb2[i] * s3 + t3;
        rF[i]    = s3;
        return;
    }
    const float* src; unsigned short* dst; const float* scale;
    int K_, N_, Kdst, koff, tx, ty, local;
    if (bid < 16)        { local = bid;      src = node_w;     dst = w_node; scale = nullptr; K_ = 64;  N_ = 256; Kdst = 64;  koff = 0;   tx = 8;  ty = 2;  }
    else if (bid < 272)  { local = bid-16;   src = gine_w1;    dst = w_g1;   scale = nullptr; K_ = 256; N_ = 256; Kdst = 256; koff = 0;   tx = 8;  ty = 8;  }
    else if (bid < 528)  { local = bid-272;  src = gine_w2;    dst = w_cat;  scale = bn1_g;   K_ = 256; N_ = 256; Kdst = 512; koff = 0;   tx = 8;  ty = 8;  }
    else if (bid < 784)  { local = bid-528;  src = attn_out_w; dst = w_cat;  scale = bn2_g;   K_ = 256; N_ = 256; Kdst = 512; koff = 256; tx = 8;  ty = 8;  }
    else if (bid < 1552) { local = bid-784;  src = attn_in_w;  dst = w_ai;   scale = nullptr; K_ = 256; N_ = 768; Kdst = 256; koff = 0;   tx = 24; ty = 8;  }
    else if (bid < 2064) { local = bid-1552; src = mlp_w1;     dst = w_m1;   scale = nullptr; K_ = 256; N_ = 512; Kdst = 256; koff = 0;   tx = 16; ty = 8;  }
    else                 { local = bid-2064; src = mlp_w2;     dst = w_m2s;  scale = bn3_g;   K_ = 512; N_ = 256; Kdst = 512; koff = 0;   tx = 8;  ty = 16; }
    int per = tx * ty;
    int l = local / per;
    int rem = local - l * per;
    int kyt = rem / tx, nxt = rem - kyt * tx;
    int n0 = nxt * 32, k0 = kyt * 32;
    const float* s = src + (size_t)l * K_ * N_;
    unsigned short* d = dst + (size_t)l * N_ * Kdst;
    int tx2 = t & 31, ty2 = t >> 5;
#pragma unroll
    for (int i = 0; i < 32; i += 8)
        tile[ty2 + i][tx2] = s[(size_t)(k0 + ty2 + i) * N_ + n0 + tx2];
    __syncthreads();
#pragma unroll
    for (int i = 0; i < 32; i += 8) {
        int n = n0 + ty2 + i;
        float sc = scale ? scale[(size_t)l * N_ + n] * BNS : 1.f;
        d[(size_t)n * Kdst + koff + k0 + tx2] = f2b(tile[tx2][ty2 + i] * sc);
    }
}

// ---------------------------------------------------------------------------
// GINE aggregation + fused g1 GEMM, v6: no h staging — gather h rows from L2
// (uniform base + 32-bit offset, coalesced 512B/row). LDS = zs 64K + mscr 8K
// -> 2 blocks/CU (32 waves). XCD-chunked swizzle keeps a graph's blocks on
// one XCD so its h panel is L2-resident. Metadata broadcast via LDS (v3).
// ---------------------------------------------------------------------------
__global__ __launch_bounds__(1024, 8)
void k_gine_g1(const unsigned short* __restrict__ hb,
               const int* __restrict__ rowptr, const uint2* __restrict__ epk,
               const float* __restrict__ ew, const float* __restrict__ eb,
               const unsigned short* __restrict__ w1,  // [256 n][256 k] bf16
               const float* __restrict__ b1,
               unsigned short* __restrict__ hid) {     // ldc 512
    __shared__ unsigned short zs16[128 * 256];         // 64 KB z tile
    __shared__ uint2 mscr[16][64];                     // 8 KB per-wave scratch
    int bid = blockIdx.x;
    int logical = (bid & 7) * (BGRAPH * 2 / 8) + (bid >> 3);   // XCD-chunked
    int g = logical >> 1, half = logical & 1;
    int t = threadIdx.x;

    int w = t >> 6, lane = t & 63;
    int d0 = lane * 4;
    float4 ew4 = *(const float4*)&ew[d0];
    float4 eb4 = *(const float4*)&eb[d0];
    uint2* ms = mscr[w];
    const unsigned short* hg = hb + (size_t)g * NNODE * DMODEL;

    const int* rp = rowptr + g * (NNODE + 1);
    int ln0 = half * 128 + w * 8;
    unsigned int zlo[8], zhi[8];
#pragma unroll 1
    for (int i = 0; i < 8; ++i) {
        int ln = ln0 + i;
        int beg = rp[ln], end = rp[ln + 1];
        float a0 = 0.f, a1 = 0.f, a2 = 0.f, a3 = 0.f;
        for (int c = beg; c < end; c += 64) {
            int cnt = min(64, end - c);
            if (lane < cnt) ms[lane] = epk[c + lane];
            asm volatile("s_waitcnt lgkmcnt(0)" ::: "memory");
#pragma unroll 4
            for (int ii = 0; ii < cnt; ++ii) {
                uint2 rec = ms[ii];                       // same addr -> broadcast
                int   sl  = (int)(rec.x & 0xffffu);
                float av  = __uint_as_float(rec.y);
                int   hoff = sl * DMODEL + d0;            // 32-bit offset, coalesced
                uint2 hv = *(const uint2*)&hg[hoff];      // L2 gather (512B/row)
                float t0 = fmaf(av, ew4.x, eb4.x);
                float t1 = fmaf(av, ew4.y, eb4.y);
                float t2 = fmaf(av, ew4.z, eb4.z);
                float t3 = fmaf(av, ew4.w, eb4.w);
                a0 += fmaxf(__uint_as_float(hv.x << 16) + t0, 0.f);
                a1 += fmaxf(__uint_as_float(hv.x & 0xffff0000u) + t1, 0.f);
                a2 += fmaxf(__uint_as_float(hv.y << 16) + t2, 0.f);
                a3 += fmaxf(__uint_as_float(hv.y & 0xffff0000u) + t3, 0.f);
            }
        }
        uint2 hv2 = *(const uint2*)&hg[ln * DMODEL + d0];
        float z0 = __uint_as_float(hv2.x << 16)         + a0;
        float z1 = __uint_as_float(hv2.x & 0xffff0000u) + a1;
        float z2 = __uint_as_float(hv2.y << 16)         + a2;
        float z3 = __uint_as_float(hv2.y & 0xffff0000u) + a3;
        asm("v_cvt_pk_bf16_f32 %0, %1, %2" : "=v"(zlo[i]) : "v"(z0), "v"(z1));
        asm("v_cvt_pk_bf16_f32 %0, %1, %2" : "=v"(zhi[i]) : "v"(z2), "v"(z3));
    }

    // ---- store z (bf16) into LDS [128][256], quad-XOR swizzled ----
    char* zs = (char*)zs16;
#pragma unroll
    for (int i = 0; i < 8; ++i) {
        int r = w * 8 + i;                       // local row 0..127
        int pq = (lane >> 1) ^ (r & 7);          // physical quad
        uint2 pk; pk.x = zlo[i]; pk.y = zhi[i];
        *(uint2*)(zs + r * 512 + (pq << 4) + ((lane & 1) << 3)) = pk;
    }
    __syncthreads();

    // ---- GEMM: hid[128 x 256] = relu(z @ W1 + b1); waves 2(M) x 8(N) ----
    int wr2 = w >> 3, wc2 = w & 7;
    int rl = lane & 15, kc = lane >> 4;
    f32x4 acc[4][2] = {};
#pragma unroll
    for (int kq = 0; kq < 8; ++kq) {             // K step = 32
        bf16x8 av[4], bv[2];
#pragma unroll
        for (int mm = 0; mm < 4; ++mm) {
            int r = wr2 * 64 + mm * 16 + rl;
            int pq = (kq * 4 + kc) ^ (r & 7);
            av[mm] = *(const bf16x8*)(zs + r * 512 + (pq << 4));
        }
#pragma unroll
        for (int nn = 0; nn < 2; ++nn) {
            int nrow = wc2 * 32 + nn * 16 + rl;
            bv[nn] = *(const bf16x8*)(w1 + (size_t)nrow * 256 + kq * 32 + kc * 8);
        }
        __builtin_amdgcn_s_setprio(1);
#pragma unroll
        for (int mm = 0; mm < 4; ++mm)
#pragma unroll
            for (int nn = 0; nn < 2; ++nn)
                acc[mm][nn] = __builtin_amdgcn_mfma_f32_16x16x32_bf16(av[mm], bv[nn], acc[mm][nn], 0, 0, 0);
        __builtin_amdgcn_s_setprio(0);
    }
    int rh = lane >> 4;
    size_t rowbase = (size_t)g * NNODE + half * 128;
#pragma unroll
    for (int nn = 0; nn < 2; ++nn) {
        int col = wc2 * 32 + nn * 16 + rl;
        float bb = b1[col];
#pragma unroll
        for (int mm = 0; mm < 4; ++mm) {
#pragma unroll
            for (int j = 0; j < 4; ++j) {
                int r = wr2 * 64 + mm * 16 + rh * 4 + j;
                float v = fmaxf(acc[mm][nn][j] + bb, 0.f);
                hid[(rowbase + r) * 512 + col] = f2b(v);
            }
        }
    }
}

// ---------------------------------------------------------------------------
// bf16 MFMA GEMM, BK=64 + chunk-XOR swizzle + XCD-chunked block swizzle.
// MODE 0: +bias   1: relu(+bias)
// ---------------------------------------------------------------------------
template <int MODE>
__global__ __launch_bounds__(256)
void k_mm(const unsigned short* __restrict__ A, const unsigned short* __restrict__ Bt,
          const float* __restrict__ bias, float* __restrict__ Cf,
          unsigned short* __restrict__ Cb, int M, int N, int K, int ldc, int gx) {
    const int BM = 128, BN = 128, BK = 64;
    __shared__ unsigned short As[BM * BK];
    __shared__ unsigned short Bs[BN * BK];

    int nwg = gridDim.x;
    int bid = blockIdx.x;
    int logical = (bid & 7) * (nwg >> 3) + (bid >> 3);   // XCD-chunked (nwg%8==0)
    int by = logical / gx, bx = logical % gx;

    int t = threadIdx.x;
    int w = t >> 6, l = t & 63;
    int wr = w >> 1, wc = w & 1;
    int bm = by * BM, bn = bx * BN;

    f32x4 acc[4][4] = {};
    int rl = l & 15, kc = l >> 4;

    for (int k0 = 0; k0 < K; k0 += BK) {
#pragma unroll
        for (int i = 0; i < 4; ++i) {
            int slot = i * 256 + t;
            int row = slot >> 3, pc = slot & 7;
            int lc = pc ^ (row & 7);
            const unsigned short* gp = A + (size_t)(bm + row) * K + k0 + lc * 8;
            __builtin_amdgcn_global_load_lds(
                (const __attribute__((address_space(1))) void*)gp,
                (__attribute__((address_space(3))) void*)&As[(i * 256 + w * 64) * 8],
                16, 0, 0);
        }
#pragma unroll
        for (int i = 0; i < 4; ++i) {
            int slot = i * 256 + t;
            int row = slot >> 3, pc = slot & 7;
            int lc = pc ^ (row & 7);
            const unsigned short* gp = Bt + (size_t)(bn + row) * K + k0 + lc * 8;
            __builtin_amdgcn_global_load_lds(
                (const __attribute__((address_space(1))) void*)gp,
                (__attribute__((address_space(3))) void*)&Bs[(i * 256 + w * 64) * 8],
                16, 0, 0);
        }
        asm volatile("s_waitcnt vmcnt(0)" ::: "memory");
        __syncthreads();

#pragma unroll
        for (int kk = 0; kk < 2; ++kk) {
            int lch = kk * 4 + kc;
            bf16x8 av[4], bv[4];
#pragma unroll
            for (int m = 0; m < 4; ++m) {
                int r = wr * 64 + m * 16 + rl;
                av[m] = *(const bf16x8*)&As[r * BK + ((lch ^ (r & 7)) << 3)];
            }
#pragma unroll
            for (int n = 0; n < 4; ++n) {
                int r = wc * 64 + n * 16 + rl;
                bv[n] = *(const bf16x8*)&Bs[r * BK + ((lch ^ (r & 7)) << 3)];
            }
#pragma unroll
            for (int m = 0; m < 4; ++m)
#pragma unroll
                for (int n = 0; n < 4; ++n)
                    acc[m][n] = __builtin_amdgcn_mfma_f32_16x16x32_bf16(av[m], bv[n], acc[m][n], 0, 0, 0);
        }
        __syncthreads();
    }

    int rh = l >> 4;
#pragma unroll
    for (int n = 0; n < 4; ++n) {
        int col = bn + wc * 64 + n * 16 + rl;
        float bv_ = bias[col];
#pragma unroll
        for (int m = 0; m < 4; ++m) {
#pragma unroll
            for (int j = 0; j < 4; ++j) {
                int row = bm + wr * 64 + m * 16 + rh * 4 + j;
                size_t idx = (size_t)row * ldc + col;
                float v = acc[m][n][j] + bv_;
                if (MODE == 1) v = fmaxf(v, 0.f);
                if (Cf) Cf[idx] = v;
                Cb[idx] = f2b(v);
            }
        }
    }
}

// ---------------------------------------------------------------------------
// MFMA attention v2: K read directly from global, no Ks LDS. 3 blocks/CU.
// ---------------------------------------------------------------------------
#define VP 264
#define OSTR 512
#define OOFF 256
__global__ __launch_bounds__(256, 3)
void k_attn(const unsigned short* __restrict__ qkv, unsigned short* __restrict__ o) {
    __shared__ unsigned short lds[8448 + 16896];  // Vt [32][264] | Ps 4x[16][264]
    unsigned short* Vt = lds;
    unsigned short* Ps = lds + 8448;

    int bh = blockIdx.x;
    int b = bh >> 3, h = bh & 7;
    int t = threadIdx.x;
    int w = t >> 6, l = t & 63;
    int rl = l & 15, kc = l >> 4;
    const float scale = 0.17677669529663687f; // 1/sqrt(32)

    const unsigned short* base = qkv + (size_t)b * NNODE * (3 * DMODEL);
    const unsigned short* Kbase = base + DMODEL + h * DHEAD;

    {
        int k0 = (t & 63) * 4, d0 = (t >> 6) * 8;
        bf16x8 vr[4];
#pragma unroll
        for (int i = 0; i < 4; ++i)
            vr[i] = *(const bf16x8*)(base + (size_t)(k0 + i) * (3 * DMODEL) + 2 * DMODEL + h * DHEAD + d0);
#pragma unroll
        for (int d = 0; d < 8; ++d) {
            ushort4 pk;
            pk.x = (unsigned short)vr[0][d];
            pk.y = (unsigned short)vr[1][d];
            pk.z = (unsigned short)vr[2][d];
            pk.w = (unsigned short)vr[3][d];
            *(ushort4*)&Vt[(d0 + d) * VP + k0] = pk;
        }
    }

    bf16x8 qv[4];
#pragma unroll
    for (int m = 0; m < 4; ++m) {
        int q = w * 64 + m * 16 + rl;
        qv[m] = *(const bf16x8*)(base + (size_t)q * (3 * DMODEL) + h * DHEAD + kc * 8);
    }
    __syncthreads();

    unsigned short* Pw = Ps + w * 16 * VP;
    f32x4 zero = {0.f, 0.f, 0.f, 0.f};

#pragma unroll 1
    for (int m = 0; m < 4; ++m) {
        f32x4 s[16];
#pragma unroll
        for (int g4 = 0; g4 < 4; ++g4) {
            bf16x8 kv[4];
#pragma unroll
            for (int i = 0; i < 4; ++i)
                kv[i] = *(const bf16x8*)(Kbase + (size_t)((g4 * 4 + i) * 16 + rl) * (3 * DMODEL) + kc * 8);
            __builtin_amdgcn_s_setprio(1);
#pragma unroll
            for (int i = 0; i < 4; ++i)
                s[g4 * 4 + i] = __builtin_amdgcn_mfma_f32_16x16x32_bf16(kv[i], qv[m], zero, 0, 0, 0);
            __builtin_amdgcn_s_setprio(0);
        }
        float mv = -1e30f;
#pragma unroll
        for (int n = 0; n < 16; ++n)
#pragma unroll
            for (int j = 0; j < 4; ++j) mv = fmaxf(mv, s[n][j]);
        mv = fmaxf(mv, __shfl_xor(mv, 16));
        mv = fmaxf(mv, __shfl_xor(mv, 32));
        float nb = -mv * scale;
        float sumv = 0.f;
#pragma unroll
        for (int n = 0; n < 16; ++n) {
            float p0 = __expf(fmaf(s[n][0], scale, nb));
            float p1 = __expf(fmaf(s[n][1], scale, nb));
            float p2 = __expf(fmaf(s[n][2], scale, nb));
            float p3 = __expf(fmaf(s[n][3], scale, nb));
            sumv += (p0 + p1) + (p2 + p3);
            unsigned int lo, hi;
            asm("v_cvt_pk_bf16_f32 %0, %1, %2" : "=v"(lo) : "v"(p0), "v"(p1));
            asm("v_cvt_pk_bf16_f32 %0, %1, %2" : "=v"(hi) : "v"(p2), "v"(p3));
            uint2 pk; pk.x = lo; pk.y = hi;
            *(uint2*)&Pw[rl * VP + n * 16 + kc * 4] = pk;
        }
        sumv += __shfl_xor(sumv, 16);
        sumv += __shfl_xor(sumv, 32);

        f32x4 o0 = zero, o1 = zero;
#pragma unroll
        for (int ks = 0; ks < 8; ++ks) {
            bf16x8 pa = *(const bf16x8*)&Pw[rl * VP + ks * 32 + kc * 8];
            bf16x8 v0 = *(const bf16x8*)&Vt[rl * VP + ks * 32 + kc * 8];
            bf16x8 v1 = *(const bf16x8*)&Vt[(16 + rl) * VP + ks * 32 + kc * 8];
            __builtin_amdgcn_s_setprio(1);
            o0 = __builtin_amdgcn_mfma_f32_16x16x32_bf16(pa, v0, o0, 0, 0, 0);
            o1 = __builtin_amdgcn_mfma_f32_16x16x32_bf16(pa, v1, o1, 0, 0, 0);
            __builtin_amdgcn_s_setprio(0);
        }
#pragma unroll
        for (int j = 0; j < 4; ++j) {
            float sj = __shfl(sumv, kc * 4 + j);
            float inv = 1.f / sj;
            int q = w * 64 + m * 16 + kc * 4 + j;
            unsigned short* orow = o + ((size_t)b * NNODE + q) * OSTR + OOFF + h * DHEAD;
            orow[rl]      = f2b(o0[j] * inv);
            orow[16 + rl] = f2b(o1[j] * inv);
        }
    }
}

// ---------------------------------------------------------------------------
// Fused tail v4 (round-18 passing): T14 register-staged double buffer.
// ---------------------------------------------------------------------------
template <int LAST>
__global__ __launch_bounds__(512)
void k_tail(const unsigned short* __restrict__ comb2,  // [NTOT][512] = [hid|o]
            const unsigned short* __restrict__ hbin,   // [NTOT][256] residual h
            const unsigned short* __restrict__ wc,     // [256][512]
            const unsigned short* __restrict__ m1,     // [512][256]
            const unsigned short* __restrict__ m2s,    // [256][512]
            const float* __restrict__ biasC, const float* __restrict__ rC,
            const float* __restrict__ b1,
            const float* __restrict__ biasF, const float* __restrict__ rF,
            unsigned short* __restrict__ hbout, float* __restrict__ outf) {
    __shared__ unsigned short WS[8192];        // 16 KB weight stage [256 rows][32 k]
    __shared__ unsigned short cmbS[32768];     // 64 KB [128][256] swz
    __shared__ unsigned short hidS[32768];     // 64 KB [128][256] swz (AS overlay)
    unsigned short* AS = hidS;                 // 8 KB activation stage (phase A only)

    int bm = blockIdx.x * 128;
    int t = threadIdx.x;
    int w = t >> 6, l = t & 63;
    int rl = l & 15, kc = l >> 4;
    int node = w * 16 + rl;                    // this lane's node (0..127)
    size_t gnode = (size_t)(bm + node);
    char* cS = (char*)cmbS;
    char* hS = (char*)hidS;

    // staging geometry (same addresses as the gload_lds version)
    int row0 = t >> 2, q0 = t & 3;
    int slot1 = 512 + t, row1 = slot1 >> 2, q1 = slot1 & 3;
    int lq0 = (q0 - (row0 >> 1)) & 3;
    int lq1 = (q1 - (row1 >> 1)) & 3;

    f32x4 accC[16] = {};

    // ================= Phase A: cmb = [hid|o] @ wc + biasC + rC*h =========
    {
        const unsigned short* wp0 = wc + (size_t)row0 * 512 + lq0 * 8;
        const unsigned short* wp1 = wc + (size_t)row1 * 512 + lq1 * 8;
        const unsigned short* ap0 = comb2 + (size_t)(bm + row0) * 512 + lq0 * 8;
        uint4 rw0 = *(const uint4*)(wp0);
        uint4 rw1 = *(const uint4*)(wp1);
        uint4 ra0 = *(const uint4*)(ap0);
        *(uint4*)&WS[t * 8]     = rw0;
        *(uint4*)&WS[slot1 * 8] = rw1;
        *(uint4*)&AS[t * 8]     = ra0;
        __syncthreads();

        f32x4 accA[16] = {};
        for (int ks = 0; ks < 16; ++ks) {
            if (ks < 15) {                      // issue next step's loads
                rw0 = *(const uint4*)(wp0 + (ks + 1) * 32);
                rw1 = *(const uint4*)(wp1 + (ks + 1) * 32);
                ra0 = *(const uint4*)(ap0 + (ks + 1) * 32);
            }
            bf16x8 b = *(const bf16x8*)&AS[node * 32 + (((kc + (node >> 1)) & 3) << 3)];
            __builtin_amdgcn_s_setprio(1);
#pragma unroll
            for (int mf = 0; mf < 16; ++mf) {
                int row = mf * 16 + rl;
                bf16x8 a = *(const bf16x8*)&WS[row * 32 + (((kc + (row >> 1)) & 3) << 3)];
                accA[mf] = __builtin_amdgcn_mfma_f32_16x16x32_bf16(a, b, accA[mf], 0, 0, 0);
            }
            __builtin_amdgcn_s_setprio(0);
            __syncthreads();
            if (ks < 15) {
                *(uint4*)&WS[t * 8]     = rw0;
                *(uint4*)&WS[slot1 * 8] = rw1;
                *(uint4*)&AS[t * 8]     = ra0;
            }
            __syncthreads();
        }
        // epilogue A -> cmbS (own-wave nodes)
#pragma unroll
        for (int mf = 0; mf < 16; ++mf) {
            int dim0 = mf * 16 + kc * 4;
            float4 bc = *(const float4*)&biasC[dim0];
            float4 rc = *(const float4*)&rC[dim0];
            uint2 hv = *(const uint2*)&hbin[gnode * 256 + dim0];
            float v0 = accA[mf][0] + bc.x + rc.x * __uint_as_float(hv.x << 16);
            float v1 = accA[mf][1] + bc.y + rc.y * __uint_as_float(hv.x & 0xffff0000u);
            float v2 = accA[mf][2] + bc.z + rc.z * __uint_as_float(hv.y << 16);
            float v3 = accA[mf][3] + bc.w + rc.w * __uint_as_float(hv.y & 0xffff0000u);
            unsigned int lo, hi;
            asm("v_cvt_pk_bf16_f32 %0, %1, %2" : "=v"(lo) : "v"(v0), "v"(v1));
            asm("v_cvt_pk_bf16_f32 %0, %1, %2" : "=v"(hi) : "v"(v2), "v"(v3));
            uint2 pk; pk.x = lo; pk.y = hi;
            int q = dim0 >> 3, half = (dim0 >> 2) & 1;
            *(uint2*)(cS + node * 512 + ((q ^ (node & 7)) << 4) + (half << 3)) = pk;
        }
    }
    __syncthreads();

    // ============ Phases B+C per 256-dim half of hid ======================
    for (int nh = 0; nh < 2; ++nh) {
        // ---- B: hidHalf = relu(cmb @ m1[nh rows] + b1) ----
        {
            const unsigned short* bp0 = m1 + (size_t)(nh * 256 + row0) * 256 + lq0 * 8;
            const unsigned short* bp1 = m1 + (size_t)(nh * 256 + row1) * 256 + lq1 * 8;
            uint4 rw0 = *(const uint4*)(bp0);
            uint4 rw1 = *(const uint4*)(bp1);
            *(uint4*)&WS[t * 8]     = rw0;
            *(uint4*)&WS[slot1 * 8] = rw1;
            __syncthreads();

            f32x4 accB[16] = {};
            for (int ks = 0; ks < 8; ++ks) {
                if (ks < 7) {
                    rw0 = *(const uint4*)(bp0 + (ks + 1) * 32);
                    rw1 = *(const uint4*)(bp1 + (ks + 1) * 32);
                }
                int kq = ks * 4 + kc;
                bf16x8 b = *(const bf16x8*)(cS + node * 512 + ((kq ^ (node & 7)) << 4));
                __builtin_amdgcn_s_setprio(1);
#pragma unroll
                for (int mf = 0; mf < 16; ++mf) {
                    int row = mf * 16 + rl;
                    bf16x8 a = *(const bf16x8*)&WS[row * 32 + (((kc + (row >> 1)) & 3) << 3)];
                    accB[mf] = __builtin_amdgcn_mfma_f32_16x16x32_bf16(a, b, accB[mf], 0, 0, 0);
                }
                __builtin_amdgcn_s_setprio(0);
                __syncthreads();
                if (ks < 7) {
                    *(uint4*)&WS[t * 8]     = rw0;
                    *(uint4*)&WS[slot1 * 8] = rw1;
                }
                __syncthreads();
            }
            // epilogue B: hidHalf = relu(accB + b1) -> hidS
#pragma unroll
            for (int mf = 0; mf < 16; ++mf) {
                int dim0 = mf * 16 + kc * 4;
                float4 bb = *(const float4*)&b1[nh * 256 + dim0];
                float v0 = fmaxf(accB[mf][0] + bb.x, 0.f);
                float v1 = fmaxf(accB[mf][1] + bb.y, 0.f);
                float v2 = fmaxf(accB[mf][2] + bb.z, 0.f);
                float v3 = fmaxf(accB[mf][3] + bb.w, 0.f);
                unsigned int lo, hi;
                asm("v_cvt_pk_bf16_f32 %0, %1, %2" : "=v"(lo) : "v"(v0), "v"(v1));
                asm("v_cvt_pk_bf16_f32 %0, %1, %2" : "=v"(hi) : "v"(v2), "v"(v3));
                uint2 pk; pk.x = lo; pk.y = hi;
                int q = dim0 >> 3, half = (dim0 >> 2) & 1;
                *(uint2*)(hS + node * 512 + ((q ^ (node & 7)) << 4) + (half << 3)) = pk;
            }
        }
        __syncthreads();
        // ---- C partial: accC += hidHalf @ m2s[nh k-slice] ----
        {
            const unsigned short* cp0 = m2s + (size_t)row0 * 512 + nh * 256 + lq0 * 8;
            const unsigned short* cp1 = m2s + (size_t)row1 * 512 + nh * 256 + lq1 * 8;
            uint4 rw0 = *(const uint4*)(cp0);
            uint4 rw1 = *(const uint4*)(cp1);
            *(uint4*)&WS[t * 8]     = rw0;
            *(uint4*)&WS[slot1 * 8] = rw1;
            __syncthreads();

            for (int ks = 0; ks < 8; ++ks) {
                if (ks < 7) {
                    rw0 = *(const uint4*)(cp0 + (ks + 1) * 32);
                    rw1 = *(const uint4*)(cp1 + (ks + 1) * 32);
                }
                int kq = ks * 4 + kc;
                bf16x8 b = *(const bf16x8*)(hS + node * 512 + ((kq ^ (node & 7)) << 4));
                __builtin_amdgcn_s_setprio(1);
#pragma unroll
                for (int mf = 0; mf < 16; ++mf) {
                    int row = mf * 16 + rl;
                    bf16x8 a = *(const bf16x8*)&WS[row * 32 + (((kc + (row >> 1)) & 3) << 3)];
                    accC[mf] = __builtin_amdgcn_mfma_f32_16x16x32_bf16(a, b, accC[mf], 0, 0, 0);
                }
                __builtin_amdgcn_s_setprio(0);
                __syncthreads();
                if (ks < 7) {
                    *(uint4*)&WS[t * 8]     = rw0;
                    *(uint4*)&WS[slot1 * 8] = rw1;
                }
                __syncthreads();
            }
        }
    }

    // ============ Epilogue C: h = accC + biasF + rF*cmb ===================
    if (LAST) {
#pragma unroll
        for (int mf = 0; mf < 16; ++mf) {
            int dim0 = mf * 16 + kc * 4;
            float4 bf_ = *(const float4*)&biasF[dim0];
            float4 rf = *(const float4*)&rF[dim0];
            int q = dim0 >> 3, half = (dim0 >> 2) & 1;
            uint2 cv = *(const uint2*)(cS + node * 512 + ((q ^ (node & 7)) << 4) + (half << 3));
            float4 o4;
            o4.x = accC[mf][0] + bf_.x + rf.x * __uint_as_float(cv.x << 16);
            o4.y = accC[mf][1] + bf_.y + rf.y * __uint_as_float(cv.x & 0xffff0000u);
            o4.z = accC[mf][2] + bf_.z + rf.z * __uint_as_float(cv.y << 16);
            o4.w = accC[mf][3] + bf_.w + rf.w * __uint_as_float(cv.y & 0xffff0000u);
            *(float4*)&outf[gnode * 256 + dim0] = o4;
        }
    } else {
        // stage into hidS (free after phase C), then coalesced copy-out
        __syncthreads();
#pragma unroll
        for (int mf = 0; mf < 16; ++mf) {
            int dim0 = mf * 16 + kc * 4;
            float4 bf_ = *(const float4*)&biasF[dim0];
            float4 rf = *(const float4*)&rF[dim0];
            int q = dim0 >> 3, half = (dim0 >> 2) & 1;
            uint2 cv = *(const uint2*)(cS + node * 512 + ((q ^ (node & 7)) << 4) + (half << 3));
            float v0 = accC[mf][0] + bf_.x + rf.x * __uint_as_float(cv.x << 16);
            float v1 = accC[mf][1] + bf_.y + rf.y * __uint_as_float(cv.x & 0xffff0000u);
            float v2 = accC[mf][2] + bf_.z + rf.z * __uint_as_float(cv.y << 16);
            float v3 = accC[mf][3] + bf_.w + rf.w * __uint_as_float(cv.y & 0xffff0000u);
            unsigned int lo, hi;
            asm("v_cvt_pk_bf16_f32 %0, %1, %2" : "=v"(lo) : "v"(v0), "v"(v1));
            asm("v_cvt_pk_bf16_f32 %0, %1, %2" : "=v"(hi) : "v"(v2), "v"(v3));
            uint2 pk; pk.x = lo; pk.y = hi;
            *(uint2*)(hS + node * 512 + ((q ^ (node & 7)) << 4) + (half << 3)) = pk;
        }
        __syncthreads();
#pragma unroll
        for (int it = 0; it < 8; ++it) {
            int slot = it * 512 + t;            // 4096 slots of 16B
            int n = slot >> 5, p = slot & 31;
            uint4 v4 = *(const uint4*)(hS + n * 512 + p * 16);
            int lq = p ^ (n & 7);
            *(uint4*)&hbout[(size_t)(bm + n) * 256 + lq * 8] = v4;
        }
    }
}

// ---------------------------------------------------------------------------
extern "C" void kernel_launch(void* const* d_in, const int* in_sizes, int n_in,
                              void* d_out, int out_size, void* d_ws, size_t ws_size,
                              hipStream_t stream) {
    const float* x          = (const float*)d_in[0];
    const float* edge_attr  = (const float*)d_in[1];
    const float* node_w     = (const float*)d_in[2];
    const float* node_b     = (const float*)d_in[3];
    const float* edge_w     = (const float*)d_in[4];
    const float* edge_b     = (const float*)d_in[5];
    const float* gine_w1    = (const float*)d_in[6];
    const float* gine_b1    = (const float*)d_in[7];
    const float* gine_w2    = (const float*)d_in[8];
    const float* gine_b2    = (const float*)d_in[9];
    const float* attn_in_w  = (const float*)d_in[10];
    const float* attn_in_b  = (const float*)d_in[11];
    const float* attn_out_w = (const float*)d_in[12];
    const float* attn_out_b = (const float*)d_in[13];
    const float* mlp_w1     = (const float*)d_in[14];
    const float* mlp_b1     = (const float*)d_in[15];
    const float* mlp_w2     = (const float*)d_in[16];
    const float* mlp_b2     = (const float*)d_in[17];
    const float* bn1_g      = (const float*)d_in[18];
    const float* bn1_b      = (const float*)d_in[19];
    const float* bn2_g      = (const float*)d_in[20];
    const float* bn2_b      = (const float*)d_in[21];
    const float* bn3_g      = (const float*)d_in[22];
    const float* bn3_b      = (const float*)d_in[23];
    const int*   edge_index = (const int*)d_in[24];

    const int* srcp = edge_index;
    const int* dstp = edge_index + EDGES;

    float* out = (float*)d_out;
    char*  ws  = (char*)d_ws;

    // ---- workspace layout ----
    size_t off = 0;
    unsigned short* hb    = (unsigned short*)(ws + off); off += (size_t)NTOT * DMODEL * 2;
    unsigned short* comb2 = (unsigned short*)(ws + off); off += (size_t)NTOT * 512 * 2;   // [hid | o]
    unsigned short* qkvb  = (unsigned short*)(ws + off); off += (size_t)NTOT * 768 * 2;
    unsigned short* xb    = (unsigned short*)(ws + off); off += (size_t)NTOT * DIN * 2;
    unsigned short* w_node = (unsigned short*)(ws + off); off += (size_t)DMODEL * DIN * 2;
    unsigned short* w_g1   = (unsigned short*)(ws + off); off += (size_t)NLAYER * DMODEL * DMODEL * 2;
    unsigned short* w_cat  = (unsigned short*)(ws + off); off += (size_t)NLAYER * DMODEL * 512 * 2;
    unsigned short* w_ai   = (unsigned short*)(ws + off); off += (size_t)NLAYER * 3 * DMODEL * DMODEL * 2;
    unsigned short* w_m1   = (unsigned short*)(ws + off); off += (size_t)NLAYER * 2 * DMODEL * DMODEL * 2;
    unsigned short* w_m2s  = (unsigned short*)(ws + off); off += (size_t)NLAYER * DMODEL * 512 * 2;
    float* biasC = (float*)(ws + off); off += (size_t)NLAYER * DMODEL * 4;
    float* rC    = (float*)(ws + off); off += (size_t)NLAYER * DMODEL * 4;
    float* biasF = (float*)(ws + off); off += (size_t)NLAYER * DMODEL * 4;
    float* rF    = (float*)(ws + off); off += (size_t)NLAYER * DMODEL * 4;
    uint2* gbuf  = (uint2*)(ws + off);  off += (size_t)BGRAPH * CAPG * 8;
    uint2* epk   = (uint2*)(ws + off);  off += (size_t)BGRAPH * CAPG * 8;
    int*   gcnt  = (int*)(ws + off);    off += (size_t)BGRAPH * 4;
    int*   rowptr = (int*)(ws + off);   off += (size_t)BGRAPH * (NNODE + 1) * 4;
    (void)ws_size; (void)in_sizes; (void)n_in; (void)out_size;

    // ---- CSR build ----
    hipMemsetAsync(gcnt, 0, (size_t)BGRAPH * 4, stream);
    k_bucket<<<EDGES / 4096, 1024, 0, stream>>>(srcp, dstp, edge_attr, gcnt, gbuf);
    k_gsort<<<BGRAPH, 1024, 0, stream>>>(gbuf, gcnt, epk, rowptr);

    // ---- merged weight/input conversion + epilogue vectors ----
    k_convall<<<4628, 256, 0, stream>>>(node_w, gine_w1, gine_w2, attn_out_w,
                                        attn_in_w, mlp_w1, mlp_w2,
                                        bn1_g, bn1_b, bn2_g, bn2_b, bn3_g, bn3_b,
                                        gine_b2, attn_out_b, mlp_b2, x,
                                        w_node, w_g1, w_cat, w_ai, w_m1, w_m2s,
                                        biasC, rC, biasF, rF, xb);

    // ---- encoder: hb = bf16(x @ node_w + node_b) ----
    k_mm<0><<<2 * (NTOT / 128), 256, 0, stream>>>(
        xb, w_node, node_b, nullptr, hb, NTOT, DMODEL, DIN, DMODEL, 2);

    for (int l = 0; l < NLAYER; ++l) {
        const unsigned short* g1 = w_g1 + (size_t)l * DMODEL * DMODEL;
        const unsigned short* wc = w_cat + (size_t)l * DMODEL * 512;
        const unsigned short* ai = w_ai + (size_t)l * 3 * DMODEL * DMODEL;
        const unsigned short* m1 = w_m1 + (size_t)l * 2 * DMODEL * DMODEL;
        const unsigned short* m2 = w_m2s + (size_t)l * DMODEL * 512;

        // GINE aggregate + g1 GEMM fused -> comb2[:, 0:256]
        k_gine_g1<<<BGRAPH * 2, 1024, 0, stream>>>(hb, rowptr, epk, edge_w, edge_b,
                                                   g1, gine_b1 + (size_t)l * DMODEL, comb2);
        // qkv = h @ attn_in_w + b -> qkvb
        k_mm<0><<<6 * (NTOT / 128), 256, 0, stream>>>(
            hb, ai, attn_in_b + (size_t)l * 3 * DMODEL, nullptr,
            qkvb, NTOT, 3 * DMODEL, DMODEL, 3 * DMODEL, 6);
        // attention -> comb2[:, 256:512]
        k_attn<<<BGRAPH * NHEAD, 256, 0, stream>>>(qkvb, comb2);
        // fused tail -> hb (+ fp32 out on last layer)
        if (l == NLAYER - 1)
            k_tail<1><<<NTOT / 128, 512, 0, stream>>>(
                comb2, hb, wc, m1, m2,
                biasC + (size_t)l * DMODEL, rC + (size_t)l * DMODEL,
                mlp_b1 + (size_t)l * 2 * DMODEL,
                biasF + (size_t)l * DMODEL, rF + (size_t)l * DMODEL,
                hb, out);
        else
            k_tail<0><<<NTOT / 128, 512, 0, stream>>>(
                comb2, hb, wc, m1, m2,
                biasC + (size_t)l * DMODEL, rC + (size_t)l * DMODEL,
                mlp_b1 + (size_t)l * 2 * DMODEL,
                biasF + (size_t)l * DMODEL, rF + (size_t)l * DMODEL,
                hb, nullptr);
    }
}

// Round 20
// 715.761 us; speedup vs baseline: 1.1673x; 1.1673x over previous
//
#include <hip/hip_runtime.h>
#include <math.h>

#define NTOT   32768
#define DMODEL 256
#define EDGES  1048576
#define BGRAPH 128
#define NNODE  256
#define NHEAD  8
#define DHEAD  32
#define NLAYER 4
#define DIN    64
#define BNS    0.9999950000374997f   // 1/sqrt(1+1e-5)
#define CAPG   9216                   // per-graph edge bucket capacity

typedef short bf16x8 __attribute__((ext_vector_type(8)));
typedef float f32x4  __attribute__((ext_vector_type(4)));

__device__ __forceinline__ unsigned short f2b(float f) {
    union { float f; unsigned int u; } v; v.f = f;
    unsigned int r = v.u + 0x7FFFu + ((v.u >> 16) & 1u);  // RNE
    return (unsigned short)(r >> 16);
}
__device__ __forceinline__ float b2f(unsigned short u) {
    union { unsigned int u; float f; } v; v.u = ((unsigned int)u) << 16;
    return v.f;
}

// ---------------------------------------------------------------------------
// Pass 1: bucket edges by graph (L2-friendly coarse scatter).
// ---------------------------------------------------------------------------
__global__ __launch_bounds__(1024)
void k_bucket(const int* __restrict__ src, const int* __restrict__ dst,
              const float* __restrict__ ea, int* __restrict__ gcnt,
              uint2* __restrict__ gbuf) {
    __shared__ int hist[BGRAPH], base[BGRAPH], cur[BGRAPH];
    int t = threadIdx.x;
    int e0 = blockIdx.x * 4096;
    if (t < BGRAPH) { hist[t] = 0; cur[t] = 0; }
    __syncthreads();
    int g4[4]; unsigned int m4[4], a4[4];
#pragma unroll
    for (int j = 0; j < 4; ++j) {
        int e = e0 + j * 1024 + t;
        int s = src[e], d = dst[e];
        g4[j] = d >> 8;
        m4[j] = (unsigned int)(s & 255) | ((unsigned int)(d & 255) << 16);
        a4[j] = __float_as_uint(ea[e]);
        atomicAdd(&hist[g4[j]], 1);
    }
    __syncthreads();
    if (t < BGRAPH) base[t] = atomicAdd(&gcnt[t], hist[t]);
    __syncthreads();
#pragma unroll
    for (int j = 0; j < 4; ++j) {
        int g = g4[j];
        int slot = base[g] + atomicAdd(&cur[g], 1);
        if (slot < CAPG) {
            uint2 r; r.x = m4[j]; r.y = a4[j];
            gbuf[(size_t)g * CAPG + slot] = r;
        }
    }
}

// ---------------------------------------------------------------------------
// Pass 2: per-graph LDS counting sort -> CSR records + rowptr.
// ---------------------------------------------------------------------------
__global__ __launch_bounds__(1024)
void k_gsort(const uint2* __restrict__ gbuf, const int* __restrict__ gcnt,
             uint2* __restrict__ epk, int* __restrict__ rowptr) {
    __shared__ int s[NNODE], excl[NNODE + 1], cur[NNODE];
    int g = blockIdx.x;
    int c = gcnt[g];
    int t = threadIdx.x;
    size_t base = (size_t)g * CAPG;
    if (t < NNODE) { s[t] = 0; cur[t] = 0; }
    __syncthreads();
    for (int i = t; i < c; i += 1024)
        atomicAdd(&s[gbuf[base + i].x >> 16], 1);
    __syncthreads();
    for (int o = 1; o < NNODE; o <<= 1) {
        int add = (t < NNODE && t >= o) ? s[t - o] : 0;
        __syncthreads();
        if (t < NNODE) s[t] += add;
        __syncthreads();
    }
    if (t < NNODE) excl[t + 1] = s[t];
    if (t == 0) excl[0] = 0;
    __syncthreads();
    if (t <= NNODE) rowptr[g * (NNODE + 1) + t] = (int)base + excl[t];
    for (int i = t; i < c; i += 1024) {
        uint2 r = gbuf[base + i];
        int dl = r.x >> 16;
        int p = excl[dl] + atomicAdd(&cur[dl], 1);
        epk[base + p] = r;
    }
}

// ---------------------------------------------------------------------------
// Merged prologue: all weight convert+transpose jobs + mkvec + x->bf16.
// ---------------------------------------------------------------------------
__global__ __launch_bounds__(256)
void k_convall(const float* __restrict__ node_w, const float* __restrict__ gine_w1,
               const float* __restrict__ gine_w2, const float* __restrict__ attn_out_w,
               const float* __restrict__ attn_in_w, const float* __restrict__ mlp_w1,
               const float* __restrict__ mlp_w2,
               const float* __restrict__ bn1_g, const float* __restrict__ bn1_b,
               const float* __restrict__ bn2_g, const float* __restrict__ bn2_b,
               const float* __restrict__ bn3_g, const float* __restrict__ bn3_b,
               const float* __restrict__ gb2, const float* __restrict__ aob,
               const float* __restrict__ mb2, const float* __restrict__ x,
               unsigned short* __restrict__ w_node, unsigned short* __restrict__ w_g1,
               unsigned short* __restrict__ w_cat, unsigned short* __restrict__ w_ai,
               unsigned short* __restrict__ w_m1, unsigned short* __restrict__ w_m2s,
               float* __restrict__ biasC, float* __restrict__ rC,
               float* __restrict__ biasF, float* __restrict__ rF,
               unsigned short* __restrict__ xb) {
    __shared__ float tile[32][33];
    int bid = blockIdx.x;
    int t = threadIdx.x;

    if (bid >= 2580) {                        // f2b: x -> xb (bf16)
        int i = ((bid - 2580) * 256 + t) * 4;
        float4 v = *(const float4*)(x + i);
        xb[i + 0] = f2b(v.x); xb[i + 1] = f2b(v.y);
        xb[i + 2] = f2b(v.z); xb[i + 3] = f2b(v.w);
        return;
    }
    if (bid >= 2576) {                        // mkvec
        int i = (bid - 2576) * 256 + t;
        float s1 = bn1_g[i] * BNS, t1 = bn1_b[i];
        float s2 = bn2_g[i] * BNS, t2 = bn2_b[i];
        float s3 = bn3_g[i] * BNS, t3 = bn3_b[i];
        biasC[i] = gb2[i] * s1 + t1 + aob[i] * s2 + t2;
        rC[i]    = s1 + s2;
        biasF[i] = mb2[i] * s3 + t3;
        rF[i]    = s3;
        return;
    }
    const float* src; unsigned short* dst; const float* scale;
    int K_, N_, Kdst, koff, tx, ty, local;
    if (bid < 16)        { local = bid;      src = node_w;     dst = w_node; scale = nullptr; K_ = 64;  N_ = 256; Kdst = 64;  koff = 0;   tx = 8;  ty = 2;  }
    else if (bid < 272)  { local = bid-16;   src = gine_w1;    dst = w_g1;   scale = nullptr; K_ = 256; N_ = 256; Kdst = 256; koff = 0;   tx = 8;  ty = 8;  }
    else if (bid < 528)  { local = bid-272;  src = gine_w2;    dst = w_cat;  scale = bn1_g;   K_ = 256; N_ = 256; Kdst = 512; koff = 0;   tx = 8;  ty = 8;  }
    else if (bid < 784)  { local = bid-528;  src = attn_out_w; dst = w_cat;  scale = bn2_g;   K_ = 256; N_ = 256; Kdst = 512; koff = 256; tx = 8;  ty = 8;  }
    else if (bid < 1552) { local = bid-784;  src = attn_in_w;  dst = w_ai;   scale = nullptr; K_ = 256; N_ = 768; Kdst = 256; koff = 0;   tx = 24; ty = 8;  }
    else if (bid < 2064) { local = bid-1552; src = mlp_w1;     dst = w_m1;   scale = nullptr; K_ = 256; N_ = 512; Kdst = 256; koff = 0;   tx = 16; ty = 8;  }
    else                 { local = bid-2064; src = mlp_w2;     dst = w_m2s;  scale = bn3_g;   K_ = 512; N_ = 256; Kdst = 512; koff = 0;   tx = 8;  ty = 16; }
    int per = tx * ty;
    int l = local / per;
    int rem = local - l * per;
    int kyt = rem / tx, nxt = rem - kyt * tx;
    int n0 = nxt * 32, k0 = kyt * 32;
    const float* s = src + (size_t)l * K_ * N_;
    unsigned short* d = dst + (size_t)l * N_ * Kdst;
    int tx2 = t & 31, ty2 = t >> 5;
#pragma unroll
    for (int i = 0; i < 32; i += 8)
        tile[ty2 + i][tx2] = s[(size_t)(k0 + ty2 + i) * N_ + n0 + tx2];
    __syncthreads();
#pragma unroll
    for (int i = 0; i < 32; i += 8) {
        int n = n0 + ty2 + i;
        float sc = scale ? scale[(size_t)l * N_ + n] * BNS : 1.f;
        d[(size_t)n * Kdst + koff + k0 + tx2] = f2b(tile[tx2][ty2 + i] * sc);
    }
}

// ---------------------------------------------------------------------------
// GINE aggregation + fused g1 GEMM, v3 (round-18 passing version).
// ---------------------------------------------------------------------------
__global__ __launch_bounds__(1024)
void k_gine_g1(const unsigned short* __restrict__ hb,
               const int* __restrict__ rowptr, const uint2* __restrict__ epk,
               const float* __restrict__ ew, const float* __restrict__ eb,
               const unsigned short* __restrict__ w1,  // [256 n][256 k] bf16
               const float* __restrict__ b1,
               unsigned short* __restrict__ hid) {     // ldc 512
    __shared__ unsigned short lds_h[NNODE * DMODEL];   // 128 KB
    __shared__ uint2 mscr[16][64];                     // 8 KB per-wave scratch
    int g = blockIdx.x >> 1, half = blockIdx.x & 1;
    int t = threadIdx.x;

    const unsigned short* gsrc = hb + (size_t)g * NNODE * DMODEL;
#pragma unroll
    for (int i = 0; i < 8; ++i) {
        int slot = i * 1024 + t;
        __builtin_amdgcn_global_load_lds(
            (const __attribute__((address_space(1))) void*)(gsrc + slot * 8),
            (__attribute__((address_space(3))) void*)&lds_h[slot * 8], 16, 0, 0);
    }
    asm volatile("s_waitcnt vmcnt(0)" ::: "memory");
    __syncthreads();

    int w = t >> 6, lane = t & 63;
    int d0 = lane * 4;
    float4 ew4 = *(const float4*)&ew[d0];
    float4 eb4 = *(const float4*)&eb[d0];
    uint2* ms = mscr[w];

    const int* rp = rowptr + g * (NNODE + 1);
    int ln0 = half * 128 + w * 8;
    unsigned int zlo[8], zhi[8];
#pragma unroll 1
    for (int i = 0; i < 8; ++i) {
        int ln = ln0 + i;
        int beg = rp[ln], end = rp[ln + 1];
        float a0 = 0.f, a1 = 0.f, a2 = 0.f, a3 = 0.f;
        for (int c = beg; c < end; c += 64) {
            int cnt = min(64, end - c);
            if (lane < cnt) ms[lane] = epk[c + lane];
            asm volatile("s_waitcnt lgkmcnt(0)" ::: "memory");
#pragma unroll 4
            for (int ii = 0; ii < cnt; ++ii) {
                uint2 rec = ms[ii];                       // same addr -> broadcast
                int   sl  = (int)(rec.x & 0xffffu);
                float av  = __uint_as_float(rec.y);
                uint2 hv = *(const uint2*)&lds_h[sl * DMODEL + d0];
                float t0 = fmaf(av, ew4.x, eb4.x);
                float t1 = fmaf(av, ew4.y, eb4.y);
                float t2 = fmaf(av, ew4.z, eb4.z);
                float t3 = fmaf(av, ew4.w, eb4.w);
                a0 += fmaxf(__uint_as_float(hv.x << 16) + t0, 0.f);
                a1 += fmaxf(__uint_as_float(hv.x & 0xffff0000u) + t1, 0.f);
                a2 += fmaxf(__uint_as_float(hv.y << 16) + t2, 0.f);
                a3 += fmaxf(__uint_as_float(hv.y & 0xffff0000u) + t3, 0.f);
            }
        }
        uint2 hv = *(const uint2*)&lds_h[ln * DMODEL + d0];
        float z0 = __uint_as_float(hv.x << 16)         + a0;
        float z1 = __uint_as_float(hv.x & 0xffff0000u) + a1;
        float z2 = __uint_as_float(hv.y << 16)         + a2;
        float z3 = __uint_as_float(hv.y & 0xffff0000u) + a3;
        asm("v_cvt_pk_bf16_f32 %0, %1, %2" : "=v"(zlo[i]) : "v"(z0), "v"(z1));
        asm("v_cvt_pk_bf16_f32 %0, %1, %2" : "=v"(zhi[i]) : "v"(z2), "v"(z3));
    }
    __syncthreads();   // all waves done reading h

    // ---- store z (bf16) into LDS [128][256] overlay, quad-XOR swizzled ----
    char* zs = (char*)lds_h;   // 64 KB region
#pragma unroll
    for (int i = 0; i < 8; ++i) {
        int r = w * 8 + i;                       // local row 0..127
        int pq = (lane >> 1) ^ (r & 7);          // physical quad
        uint2 pk; pk.x = zlo[i]; pk.y = zhi[i];
        *(uint2*)(zs + r * 512 + (pq << 4) + ((lane & 1) << 3)) = pk;
    }
    __syncthreads();

    // ---- GEMM: hid[128 x 256] = relu(z @ W1 + b1); waves 2(M) x 8(N) ----
    int wr2 = w >> 3, wc2 = w & 7;
    int rl = lane & 15, kc = lane >> 4;
    f32x4 acc[4][2] = {};
#pragma unroll
    for (int kq = 0; kq < 8; ++kq) {             // K step = 32
        bf16x8 av[4], bv[2];
#pragma unroll
        for (int mm = 0; mm < 4; ++mm) {
            int r = wr2 * 64 + mm * 16 + rl;
            int pq = (kq * 4 + kc) ^ (r & 7);
            av[mm] = *(const bf16x8*)(zs + r * 512 + (pq << 4));
        }
#pragma unroll
        for (int nn = 0; nn < 2; ++nn) {
            int nrow = wc2 * 32 + nn * 16 + rl;
            bv[nn] = *(const bf16x8*)(w1 + (size_t)nrow * 256 + kq * 32 + kc * 8);
        }
        __builtin_amdgcn_s_setprio(1);
#pragma unroll
        for (int mm = 0; mm < 4; ++mm)
#pragma unroll
            for (int nn = 0; nn < 2; ++nn)
                acc[mm][nn] = __builtin_amdgcn_mfma_f32_16x16x32_bf16(av[mm], bv[nn], acc[mm][nn], 0, 0, 0);
        __builtin_amdgcn_s_setprio(0);
    }
    int rh = lane >> 4;
    size_t rowbase = (size_t)g * NNODE + half * 128;
#pragma unroll
    for (int nn = 0; nn < 2; ++nn) {
        int col = wc2 * 32 + nn * 16 + rl;
        float bb = b1[col];
#pragma unroll
        for (int mm = 0; mm < 4; ++mm) {
#pragma unroll
            for (int j = 0; j < 4; ++j) {
                int r = wr2 * 64 + mm * 16 + rh * 4 + j;
                float v = fmaxf(acc[mm][nn][j] + bb, 0.f);
                hid[(rowbase + r) * 512 + col] = f2b(v);
            }
        }
    }
}

// ---------------------------------------------------------------------------
// bf16 MFMA GEMM, BK=64 + chunk-XOR swizzle + XCD-chunked block swizzle.
// MODE 0: +bias   1: relu(+bias)
// ---------------------------------------------------------------------------
template <int MODE>
__global__ __launch_bounds__(256)
void k_mm(const unsigned short* __restrict__ A, const unsigned short* __restrict__ Bt,
          const float* __restrict__ bias, float* __restrict__ Cf,
          unsigned short* __restrict__ Cb, int M, int N, int K, int ldc, int gx) {
    const int BM = 128, BN = 128, BK = 64;
    __shared__ unsigned short As[BM * BK];
    __shared__ unsigned short Bs[BN * BK];

    int nwg = gridDim.x;
    int bid = blockIdx.x;
    int logical = (bid & 7) * (nwg >> 3) + (bid >> 3);   // XCD-chunked (nwg%8==0)
    int by = logical / gx, bx = logical % gx;

    int t = threadIdx.x;
    int w = t >> 6, l = t & 63;
    int wr = w >> 1, wc = w & 1;
    int bm = by * BM, bn = bx * BN;

    f32x4 acc[4][4] = {};
    int rl = l & 15, kc = l >> 4;

    for (int k0 = 0; k0 < K; k0 += BK) {
#pragma unroll
        for (int i = 0; i < 4; ++i) {
            int slot = i * 256 + t;
            int row = slot >> 3, pc = slot & 7;
            int lc = pc ^ (row & 7);
            const unsigned short* gp = A + (size_t)(bm + row) * K + k0 + lc * 8;
            __builtin_amdgcn_global_load_lds(
                (const __attribute__((address_space(1))) void*)gp,
                (__attribute__((address_space(3))) void*)&As[(i * 256 + w * 64) * 8],
                16, 0, 0);
        }
#pragma unroll
        for (int i = 0; i < 4; ++i) {
            int slot = i * 256 + t;
            int row = slot >> 3, pc = slot & 7;
            int lc = pc ^ (row & 7);
            const unsigned short* gp = Bt + (size_t)(bn + row) * K + k0 + lc * 8;
            __builtin_amdgcn_global_load_lds(
                (const __attribute__((address_space(1))) void*)gp,
                (__attribute__((address_space(3))) void*)&Bs[(i * 256 + w * 64) * 8],
                16, 0, 0);
        }
        asm volatile("s_waitcnt vmcnt(0)" ::: "memory");
        __syncthreads();

#pragma unroll
        for (int kk = 0; kk < 2; ++kk) {
            int lch = kk * 4 + kc;
            bf16x8 av[4], bv[4];
#pragma unroll
            for (int m = 0; m < 4; ++m) {
                int r = wr * 64 + m * 16 + rl;
                av[m] = *(const bf16x8*)&As[r * BK + ((lch ^ (r & 7)) << 3)];
            }
#pragma unroll
            for (int n = 0; n < 4; ++n) {
                int r = wc * 64 + n * 16 + rl;
                bv[n] = *(const bf16x8*)&Bs[r * BK + ((lch ^ (r & 7)) << 3)];
            }
#pragma unroll
            for (int m = 0; m < 4; ++m)
#pragma unroll
                for (int n = 0; n < 4; ++n)
                    acc[m][n] = __builtin_amdgcn_mfma_f32_16x16x32_bf16(av[m], bv[n], acc[m][n], 0, 0, 0);
        }
        __syncthreads();
    }

    int rh = l >> 4;
#pragma unroll
    for (int n = 0; n < 4; ++n) {
        int col = bn + wc * 64 + n * 16 + rl;
        float bv_ = bias[col];
#pragma unroll
        for (int m = 0; m < 4; ++m) {
#pragma unroll
            for (int j = 0; j < 4; ++j) {
                int row = bm + wr * 64 + m * 16 + rh * 4 + j;
                size_t idx = (size_t)row * ldc + col;
                float v = acc[m][n][j] + bv_;
                if (MODE == 1) v = fmaxf(v, 0.f);
                if (Cf) Cf[idx] = v;
                Cb[idx] = f2b(v);
            }
        }
    }
}

// ---------------------------------------------------------------------------
// MFMA attention v2: K read directly from global, no Ks LDS. 3 blocks/CU.
// ---------------------------------------------------------------------------
#define VP 264
#define OSTR 512
#define OOFF 256
__global__ __launch_bounds__(256, 3)
void k_attn(const unsigned short* __restrict__ qkv, unsigned short* __restrict__ o) {
    __shared__ unsigned short lds[8448 + 16896];  // Vt [32][264] | Ps 4x[16][264]
    unsigned short* Vt = lds;
    unsigned short* Ps = lds + 8448;

    int bh = blockIdx.x;
    int b = bh >> 3, h = bh & 7;
    int t = threadIdx.x;
    int w = t >> 6, l = t & 63;
    int rl = l & 15, kc = l >> 4;
    const float scale = 0.17677669529663687f; // 1/sqrt(32)

    const unsigned short* base = qkv + (size_t)b * NNODE * (3 * DMODEL);
    const unsigned short* Kbase = base + DMODEL + h * DHEAD;

    {
        int k0 = (t & 63) * 4, d0 = (t >> 6) * 8;
        bf16x8 vr[4];
#pragma unroll
        for (int i = 0; i < 4; ++i)
            vr[i] = *(const bf16x8*)(base + (size_t)(k0 + i) * (3 * DMODEL) + 2 * DMODEL + h * DHEAD + d0);
#pragma unroll
        for (int d = 0; d < 8; ++d) {
            ushort4 pk;
            pk.x = (unsigned short)vr[0][d];
            pk.y = (unsigned short)vr[1][d];
            pk.z = (unsigned short)vr[2][d];
            pk.w = (unsigned short)vr[3][d];
            *(ushort4*)&Vt[(d0 + d) * VP + k0] = pk;
        }
    }

    bf16x8 qv[4];
#pragma unroll
    for (int m = 0; m < 4; ++m) {
        int q = w * 64 + m * 16 + rl;
        qv[m] = *(const bf16x8*)(base + (size_t)q * (3 * DMODEL) + h * DHEAD + kc * 8);
    }
    __syncthreads();

    unsigned short* Pw = Ps + w * 16 * VP;
    f32x4 zero = {0.f, 0.f, 0.f, 0.f};

#pragma unroll 1
    for (int m = 0; m < 4; ++m) {
        f32x4 s[16];
#pragma unroll
        for (int g4 = 0; g4 < 4; ++g4) {
            bf16x8 kv[4];
#pragma unroll
            for (int i = 0; i < 4; ++i)
                kv[i] = *(const bf16x8*)(Kbase + (size_t)((g4 * 4 + i) * 16 + rl) * (3 * DMODEL) + kc * 8);
            __builtin_amdgcn_s_setprio(1);
#pragma unroll
            for (int i = 0; i < 4; ++i)
                s[g4 * 4 + i] = __builtin_amdgcn_mfma_f32_16x16x32_bf16(kv[i], qv[m], zero, 0, 0, 0);
            __builtin_amdgcn_s_setprio(0);
        }
        float mv = -1e30f;
#pragma unroll
        for (int n = 0; n < 16; ++n)
#pragma unroll
            for (int j = 0; j < 4; ++j) mv = fmaxf(mv, s[n][j]);
        mv = fmaxf(mv, __shfl_xor(mv, 16));
        mv = fmaxf(mv, __shfl_xor(mv, 32));
        float nb = -mv * scale;
        float sumv = 0.f;
#pragma unroll
        for (int n = 0; n < 16; ++n) {
            float p0 = __expf(fmaf(s[n][0], scale, nb));
            float p1 = __expf(fmaf(s[n][1], scale, nb));
            float p2 = __expf(fmaf(s[n][2], scale, nb));
            float p3 = __expf(fmaf(s[n][3], scale, nb));
            sumv += (p0 + p1) + (p2 + p3);
            unsigned int lo, hi;
            asm("v_cvt_pk_bf16_f32 %0, %1, %2" : "=v"(lo) : "v"(p0), "v"(p1));
            asm("v_cvt_pk_bf16_f32 %0, %1, %2" : "=v"(hi) : "v"(p2), "v"(p3));
            uint2 pk; pk.x = lo; pk.y = hi;
            *(uint2*)&Pw[rl * VP + n * 16 + kc * 4] = pk;
        }
        sumv += __shfl_xor(sumv, 16);
        sumv += __shfl_xor(sumv, 32);

        f32x4 o0 = zero, o1 = zero;
#pragma unroll
        for (int ks = 0; ks < 8; ++ks) {
            bf16x8 pa = *(const bf16x8*)&Pw[rl * VP + ks * 32 + kc * 8];
            bf16x8 v0 = *(const bf16x8*)&Vt[rl * VP + ks * 32 + kc * 8];
            bf16x8 v1 = *(const bf16x8*)&Vt[(16 + rl) * VP + ks * 32 + kc * 8];
            __builtin_amdgcn_s_setprio(1);
            o0 = __builtin_amdgcn_mfma_f32_16x16x32_bf16(pa, v0, o0, 0, 0, 0);
            o1 = __builtin_amdgcn_mfma_f32_16x16x32_bf16(pa, v1, o1, 0, 0, 0);
            __builtin_amdgcn_s_setprio(0);
        }
#pragma unroll
        for (int j = 0; j < 4; ++j) {
            float sj = __shfl(sumv, kc * 4 + j);
            float inv = 1.f / sj;
            int q = w * 64 + m * 16 + kc * 4 + j;
            unsigned short* orow = o + ((size_t)b * NNODE + q) * OSTR + OOFF + h * DHEAD;
            orow[rl]      = f2b(o0[j] * inv);
            orow[16 + rl] = f2b(o1[j] * inv);
        }
    }
}

// ---------------------------------------------------------------------------
// Fused tail v4 (round-18 passing): T14 register-staged double buffer.
// ---------------------------------------------------------------------------
template <int LAST>
__global__ __launch_bounds__(512)
void k_tail(const unsigned short* __restrict__ comb2,  // [NTOT][512] = [hid|o]
            const unsigned short* __restrict__ hbin,   // [NTOT][256] residual h
            const unsigned short* __restrict__ wc,     // [256][512]
            const unsigned short* __restrict__ m1,     // [512][256]
            const unsigned short* __restrict__ m2s,    // [256][512]
            const float* __restrict__ biasC, const float* __restrict__ rC,
            const float* __restrict__ b1,
            const float* __restrict__ biasF, const float* __restrict__ rF,
            unsigned short* __restrict__ hbout, float* __restrict__ outf) {
    __shared__ unsigned short WS[8192];        // 16 KB weight stage [256 rows][32 k]
    __shared__ unsigned short cmbS[32768];     // 64 KB [128][256] swz
    __shared__ unsigned short hidS[32768];     // 64 KB [128][256] swz (AS overlay)
    unsigned short* AS = hidS;                 // 8 KB activation stage (phase A only)

    int bm = blockIdx.x * 128;
    int t = threadIdx.x;
    int w = t >> 6, l = t & 63;
    int rl = l & 15, kc = l >> 4;
    int node = w * 16 + rl;                    // this lane's node (0..127)
    size_t gnode = (size_t)(bm + node);
    char* cS = (char*)cmbS;
    char* hS = (char*)hidS;

    // staging geometry (same addresses as the gload_lds version)
    int row0 = t >> 2, q0 = t & 3;
    int slot1 = 512 + t, row1 = slot1 >> 2, q1 = slot1 & 3;
    int lq0 = (q0 - (row0 >> 1)) & 3;
    int lq1 = (q1 - (row1 >> 1)) & 3;

    f32x4 accC[16] = {};

    // ================= Phase A: cmb = [hid|o] @ wc + biasC + rC*h =========
    {
        const unsigned short* wp0 = wc + (size_t)row0 * 512 + lq0 * 8;
        const unsigned short* wp1 = wc + (size_t)row1 * 512 + lq1 * 8;
        const unsigned short* ap0 = comb2 + (size_t)(bm + row0) * 512 + lq0 * 8;
        uint4 rw0 = *(const uint4*)(wp0);
        uint4 rw1 = *(const uint4*)(wp1);
        uint4 ra0 = *(const uint4*)(ap0);
        *(uint4*)&WS[t * 8]     = rw0;
        *(uint4*)&WS[slot1 * 8] = rw1;
        *(uint4*)&AS[t * 8]     = ra0;
        __syncthreads();

        f32x4 accA[16] = {};
        for (int ks = 0; ks < 16; ++ks) {
            if (ks < 15) {                      // issue next step's loads
                rw0 = *(const uint4*)(wp0 + (ks + 1) * 32);
                rw1 = *(const uint4*)(wp1 + (ks + 1) * 32);
                ra0 = *(const uint4*)(ap0 + (ks + 1) * 32);
            }
            bf16x8 b = *(const bf16x8*)&AS[node * 32 + (((kc + (node >> 1)) & 3) << 3)];
            __builtin_amdgcn_s_setprio(1);
#pragma unroll
            for (int mf = 0; mf < 16; ++mf) {
                int row = mf * 16 + rl;
                bf16x8 a = *(const bf16x8*)&WS[row * 32 + (((kc + (row >> 1)) & 3) << 3)];
                accA[mf] = __builtin_amdgcn_mfma_f32_16x16x32_bf16(a, b, accA[mf], 0, 0, 0);
            }
            __builtin_amdgcn_s_setprio(0);
            __syncthreads();
            if (ks < 15) {
                *(uint4*)&WS[t * 8]     = rw0;
                *(uint4*)&WS[slot1 * 8] = rw1;
                *(uint4*)&AS[t * 8]     = ra0;
            }
            __syncthreads();
        }
        // epilogue A -> cmbS (own-wave nodes)
#pragma unroll
        for (int mf = 0; mf < 16; ++mf) {
            int dim0 = mf * 16 + kc * 4;
            float4 bc = *(const float4*)&biasC[dim0];
            float4 rc = *(const float4*)&rC[dim0];
            uint2 hv = *(const uint2*)&hbin[gnode * 256 + dim0];
            float v0 = accA[mf][0] + bc.x + rc.x * __uint_as_float(hv.x << 16);
            float v1 = accA[mf][1] + bc.y + rc.y * __uint_as_float(hv.x & 0xffff0000u);
            float v2 = accA[mf][2] + bc.z + rc.z * __uint_as_float(hv.y << 16);
            float v3 = accA[mf][3] + bc.w + rc.w * __uint_as_float(hv.y & 0xffff0000u);
            unsigned int lo, hi;
            asm("v_cvt_pk_bf16_f32 %0, %1, %2" : "=v"(lo) : "v"(v0), "v"(v1));
            asm("v_cvt_pk_bf16_f32 %0, %1, %2" : "=v"(hi) : "v"(v2), "v"(v3));
            uint2 pk; pk.x = lo; pk.y = hi;
            int q = dim0 >> 3, half = (dim0 >> 2) & 1;
            *(uint2*)(cS + node * 512 + ((q ^ (node & 7)) << 4) + (half << 3)) = pk;
        }
    }
    __syncthreads();

    // ============ Phases B+C per 256-dim half of hid ======================
    for (int nh = 0; nh < 2; ++nh) {
        // ---- B: hidHalf = relu(cmb @ m1[nh rows] + b1) ----
        {
            const unsigned short* bp0 = m1 + (size_t)(nh * 256 + row0) * 256 + lq0 * 8;
            const unsigned short* bp1 = m1 + (size_t)(nh * 256 + row1) * 256 + lq1 * 8;
            uint4 rw0 = *(const uint4*)(bp0);
            uint4 rw1 = *(const uint4*)(bp1);
            *(uint4*)&WS[t * 8]     = rw0;
            *(uint4*)&WS[slot1 * 8] = rw1;
            __syncthreads();

            f32x4 accB[16] = {};
            for (int ks = 0; ks < 8; ++ks) {
                if (ks < 7) {
                    rw0 = *(const uint4*)(bp0 + (ks + 1) * 32);
                    rw1 = *(const uint4*)(bp1 + (ks + 1) * 32);
                }
                int kq = ks * 4 + kc;
                bf16x8 b = *(const bf16x8*)(cS + node * 512 + ((kq ^ (node & 7)) << 4));
                __builtin_amdgcn_s_setprio(1);
#pragma unroll
                for (int mf = 0; mf < 16; ++mf) {
                    int row = mf * 16 + rl;
                    bf16x8 a = *(const bf16x8*)&WS[row * 32 + (((kc + (row >> 1)) & 3) << 3)];
                    accB[mf] = __builtin_amdgcn_mfma_f32_16x16x32_bf16(a, b, accB[mf], 0, 0, 0);
                }
                __builtin_amdgcn_s_setprio(0);
                __syncthreads();
                if (ks < 7) {
                    *(uint4*)&WS[t * 8]     = rw0;
                    *(uint4*)&WS[slot1 * 8] = rw1;
                }
                __syncthreads();
            }
            // epilogue B: hidHalf = relu(accB + b1) -> hidS
#pragma unroll
            for (int mf = 0; mf < 16; ++mf) {
                int dim0 = mf * 16 + kc * 4;
                float4 bb = *(const float4*)&b1[nh * 256 + dim0];
                float v0 = fmaxf(accB[mf][0] + bb.x, 0.f);
                float v1 = fmaxf(accB[mf][1] + bb.y, 0.f);
                float v2 = fmaxf(accB[mf][2] + bb.z, 0.f);
                float v3 = fmaxf(accB[mf][3] + bb.w, 0.f);
                unsigned int lo, hi;
                asm("v_cvt_pk_bf16_f32 %0, %1, %2" : "=v"(lo) : "v"(v0), "v"(v1));
                asm("v_cvt_pk_bf16_f32 %0, %1, %2" : "=v"(hi) : "v"(v2), "v"(v3));
                uint2 pk; pk.x = lo; pk.y = hi;
                int q = dim0 >> 3, half = (dim0 >> 2) & 1;
                *(uint2*)(hS + node * 512 + ((q ^ (node & 7)) << 4) + (half << 3)) = pk;
            }
        }
        __syncthreads();
        // ---- C partial: accC += hidHalf @ m2s[nh k-slice] ----
        {
            const unsigned short* cp0 = m2s + (size_t)row0 * 512 + nh * 256 + lq0 * 8;
            const unsigned short* cp1 = m2s + (size_t)row1 * 512 + nh * 256 + lq1 * 8;
            uint4 rw0 = *(const uint4*)(cp0);
            uint4 rw1 = *(const uint4*)(cp1);
            *(uint4*)&WS[t * 8]     = rw0;
            *(uint4*)&WS[slot1 * 8] = rw1;
            __syncthreads();

            for (int ks = 0; ks < 8; ++ks) {
                if (ks < 7) {
                    rw0 = *(const uint4*)(cp0 + (ks + 1) * 32);
                    rw1 = *(const uint4*)(cp1 + (ks + 1) * 32);
                }
                int kq = ks * 4 + kc;
                bf16x8 b = *(const bf16x8*)(hS + node * 512 + ((kq ^ (node & 7)) << 4));
                __builtin_amdgcn_s_setprio(1);
#pragma unroll
                for (int mf = 0; mf < 16; ++mf) {
                    int row = mf * 16 + rl;
                    bf16x8 a = *(const bf16x8*)&WS[row * 32 + (((kc + (row >> 1)) & 3) << 3)];
                    accC[mf] = __builtin_amdgcn_mfma_f32_16x16x32_bf16(a, b, accC[mf], 0, 0, 0);
                }
                __builtin_amdgcn_s_setprio(0);
                __syncthreads();
                if (ks < 7) {
                    *(uint4*)&WS[t * 8]     = rw0;
                    *(uint4*)&WS[slot1 * 8] = rw1;
                }
                __syncthreads();
            }
        }
    }

    // ============ Epilogue C: h = accC + biasF + rF*cmb ===================
    if (LAST) {
#pragma unroll
        for (int mf = 0; mf < 16; ++mf) {
            int dim0 = mf * 16 + kc * 4;
            float4 bf_ = *(const float4*)&biasF[dim0];
            float4 rf = *(const float4*)&rF[dim0];
            int q = dim0 >> 3, half = (dim0 >> 2) & 1;
            uint2 cv = *(const uint2*)(cS + node * 512 + ((q ^ (node & 7)) << 4) + (half << 3));
            float4 o4;
            o4.x = accC[mf][0] + bf_.x + rf.x * __uint_as_float(cv.x << 16);
            o4.y = accC[mf][1] + bf_.y + rf.y * __uint_as_float(cv.x & 0xffff0000u);
            o4.z = accC[mf][2] + bf_.z + rf.z * __uint_as_float(cv.y << 16);
            o4.w = accC[mf][3] + bf_.w + rf.w * __uint_as_float(cv.y & 0xffff0000u);
            *(float4*)&outf[gnode * 256 + dim0] = o4;
        }
    } else {
        // stage into hidS (free after phase C), then coalesced copy-out
        __syncthreads();
#pragma unroll
        for (int mf = 0; mf < 16; ++mf) {
            int dim0 = mf * 16 + kc * 4;
            float4 bf_ = *(const float4*)&biasF[dim0];
            float4 rf = *(const float4*)&rF[dim0];
            int q = dim0 >> 3, half = (dim0 >> 2) & 1;
            uint2 cv = *(const uint2*)(cS + node * 512 + ((q ^ (node & 7)) << 4) + (half << 3));
            float v0 = accC[mf][0] + bf_.x + rf.x * __uint_as_float(cv.x << 16);
            float v1 = accC[mf][1] + bf_.y + rf.y * __uint_as_float(cv.x & 0xffff0000u);
            float v2 = accC[mf][2] + bf_.z + rf.z * __uint_as_float(cv.y << 16);
            float v3 = accC[mf][3] + bf_.w + rf.w * __uint_as_float(cv.y & 0xffff0000u);
            unsigned int lo, hi;
            asm("v_cvt_pk_bf16_f32 %0, %1, %2" : "=v"(lo) : "v"(v0), "v"(v1));
            asm("v_cvt_pk_bf16_f32 %0, %1, %2" : "=v"(hi) : "v"(v2), "v"(v3));
            uint2 pk; pk.x = lo; pk.y = hi;
            *(uint2*)(hS + node * 512 + ((q ^ (node & 7)) << 4) + (half << 3)) = pk;
        }
        __syncthreads();
#pragma unroll
        for (int it = 0; it < 8; ++it) {
            int slot = it * 512 + t;            // 4096 slots of 16B
            int n = slot >> 5, p = slot & 31;
            uint4 v4 = *(const uint4*)(hS + n * 512 + p * 16);
            int lq = p ^ (n & 7);
            *(uint4*)&hbout[(size_t)(bm + n) * 256 + lq * 8] = v4;
        }
    }
}

// ---------------------------------------------------------------------------
extern "C" void kernel_launch(void* const* d_in, const int* in_sizes, int n_in,
                              void* d_out, int out_size, void* d_ws, size_t ws_size,
                              hipStream_t stream) {
    const float* x          = (const float*)d_in[0];
    const float* edge_attr  = (const float*)d_in[1];
    const float* node_w     = (const float*)d_in[2];
    const float* node_b     = (const float*)d_in[3];
    const float* edge_w     = (const float*)d_in[4];
    const float* edge_b     = (const float*)d_in[5];
    const float* gine_w1    = (const float*)d_in[6];
    const float* gine_b1    = (const float*)d_in[7];
    const float* gine_w2    = (const float*)d_in[8];
    const float* gine_b2    = (const float*)d_in[9];
    const float* attn_in_w  = (const float*)d_in[10];
    const float* attn_in_b  = (const float*)d_in[11];
    const float* attn_out_w = (const float*)d_in[12];
    const float* attn_out_b = (const float*)d_in[13];
    const float* mlp_w1     = (const float*)d_in[14];
    const float* mlp_b1     = (const float*)d_in[15];
    const float* mlp_w2     = (const float*)d_in[16];
    const float* mlp_b2     = (const float*)d_in[17];
    const float* bn1_g      = (const float*)d_in[18];
    const float* bn1_b      = (const float*)d_in[19];
    const float* bn2_g      = (const float*)d_in[20];
    const float* bn2_b      = (const float*)d_in[21];
    const float* bn3_g      = (const float*)d_in[22];
    const float* bn3_b      = (const float*)d_in[23];
    const int*   edge_index = (const int*)d_in[24];

    const int* srcp = edge_index;
    const int* dstp = edge_index + EDGES;

    float* out = (float*)d_out;
    char*  ws  = (char*)d_ws;

    // ---- workspace layout ----
    size_t off = 0;
    unsigned short* hb    = (unsigned short*)(ws + off); off += (size_t)NTOT * DMODEL * 2;
    unsigned short* comb2 = (unsigned short*)(ws + off); off += (size_t)NTOT * 512 * 2;   // [hid | o]
    unsigned short* qkvb  = (unsigned short*)(ws + off); off += (size_t)NTOT * 768 * 2;
    unsigned short* xb    = (unsigned short*)(ws + off); off += (size_t)NTOT * DIN * 2;
    unsigned short* w_node = (unsigned short*)(ws + off); off += (size_t)DMODEL * DIN * 2;
    unsigned short* w_g1   = (unsigned short*)(ws + off); off += (size_t)NLAYER * DMODEL * DMODEL * 2;
    unsigned short* w_cat  = (unsigned short*)(ws + off); off += (size_t)NLAYER * DMODEL * 512 * 2;
    unsigned short* w_ai   = (unsigned short*)(ws + off); off += (size_t)NLAYER * 3 * DMODEL * DMODEL * 2;
    unsigned short* w_m1   = (unsigned short*)(ws + off); off += (size_t)NLAYER * 2 * DMODEL * DMODEL * 2;
    unsigned short* w_m2s  = (unsigned short*)(ws + off); off += (size_t)NLAYER * DMODEL * 512 * 2;
    float* biasC = (float*)(ws + off); off += (size_t)NLAYER * DMODEL * 4;
    float* rC    = (float*)(ws + off); off += (size_t)NLAYER * DMODEL * 4;
    float* biasF = (float*)(ws + off); off += (size_t)NLAYER * DMODEL * 4;
    float* rF    = (float*)(ws + off); off += (size_t)NLAYER * DMODEL * 4;
    uint2* gbuf  = (uint2*)(ws + off);  off += (size_t)BGRAPH * CAPG * 8;
    uint2* epk   = (uint2*)(ws + off);  off += (size_t)BGRAPH * CAPG * 8;
    int*   gcnt  = (int*)(ws + off);    off += (size_t)BGRAPH * 4;
    int*   rowptr = (int*)(ws + off);   off += (size_t)BGRAPH * (NNODE + 1) * 4;
    (void)ws_size; (void)in_sizes; (void)n_in; (void)out_size;

    // ---- CSR build ----
    hipMemsetAsync(gcnt, 0, (size_t)BGRAPH * 4, stream);
    k_bucket<<<EDGES / 4096, 1024, 0, stream>>>(srcp, dstp, edge_attr, gcnt, gbuf);
    k_gsort<<<BGRAPH, 1024, 0, stream>>>(gbuf, gcnt, epk, rowptr);

    // ---- merged weight/input conversion + epilogue vectors ----
    k_convall<<<4628, 256, 0, stream>>>(node_w, gine_w1, gine_w2, attn_out_w,
                                        attn_in_w, mlp_w1, mlp_w2,
                                        bn1_g, bn1_b, bn2_g, bn2_b, bn3_g, bn3_b,
                                        gine_b2, attn_out_b, mlp_b2, x,
                                        w_node, w_g1, w_cat, w_ai, w_m1, w_m2s,
                                        biasC, rC, biasF, rF, xb);

    // ---- encoder: hb = bf16(x @ node_w + node_b) ----
    k_mm<0><<<2 * (NTOT / 128), 256, 0, stream>>>(
        xb, w_node, node_b, nullptr, hb, NTOT, DMODEL, DIN, DMODEL, 2);

    for (int l = 0; l < NLAYER; ++l) {
        const unsigned short* g1 = w_g1 + (size_t)l * DMODEL * DMODEL;
        const unsigned short* wc = w_cat + (size_t)l * DMODEL * 512;
        const unsigned short* ai = w_ai + (size_t)l * 3 * DMODEL * DMODEL;
        const unsigned short* m1 = w_m1 + (size_t)l * 2 * DMODEL * DMODEL;
        const unsigned short* m2 = w_m2s + (size_t)l * DMODEL * 512;

        // GINE aggregate + g1 GEMM fused -> comb2[:, 0:256]
        k_gine_g1<<<BGRAPH * 2, 1024, 0, stream>>>(hb, rowptr, epk, edge_w, edge_b,
                                                   g1, gine_b1 + (size_t)l * DMODEL, comb2);
        // qkv = h @ attn_in_w + b -> qkvb
        k_mm<0><<<6 * (NTOT / 128), 256, 0, stream>>>(
            hb, ai, attn_in_b + (size_t)l * 3 * DMODEL, nullptr,
            qkvb, NTOT, 3 * DMODEL, DMODEL, 3 * DMODEL, 6);
        // attention -> comb2[:, 256:512]
        k_attn<<<BGRAPH * NHEAD, 256, 0, stream>>>(qkvb, comb2);
        // fused tail -> hb (+ fp32 out on last layer)
        if (l == NLAYER - 1)
            k_tail<1><<<NTOT / 128, 512, 0, stream>>>(
                comb2, hb, wc, m1, m2,
                biasC + (size_t)l * DMODEL, rC + (size_t)l * DMODEL,
                mlp_b1 + (size_t)l * 2 * DMODEL,
                biasF + (size_t)l * DMODEL, rF + (size_t)l * DMODEL,
                hb, out);
        else
            k_tail<0><<<NTOT / 128, 512, 0, stream>>>(
                comb2, hb, wc, m1, m2,
                biasC + (size_t)l * DMODEL, rC + (size_t)l * DMODEL,
                mlp_b1 + (size_t)l * 2 * DMODEL,
                biasF + (size_t)l * DMODEL, rF + (size_t)l * DMODEL,
                hb, nullptr);
    }
}